// Round 1
// baseline (1195.996 us; speedup 1.0000x reference)
//
#include <hip/hip_runtime.h>
#include <hip/hip_bf16.h>

#define N_ 50000
#define E_ 800000
#define IN_ 128
#define OUT_ 128
#define ASSIGN_ 256
#define B_ 32
#define KTOT 256     // 2*IN
#define JTOT 384     // OUT + ASSIGN

// ---------------- histogram: deg[dst]++ and (gs,gd) bucket counts ----------------
__global__ void k_hist(const int* __restrict__ ei, int* __restrict__ deg,
                       int* __restrict__ binCount) {
    __shared__ int lh[1024];
    int t = threadIdx.x;
    for (int i = t; i < 1024; i += 256) lh[i] = 0;
    __syncthreads();
    int e = blockIdx.x * 256 + t;
    if (e < E_) {
        int s = ei[e], d = ei[E_ + e];
        atomicAdd(&deg[d], 1);
        int gs = (s * B_) / N_, gd = (d * B_) / N_;
        atomicAdd(&lh[gs * 32 + gd], 1);
    }
    __syncthreads();
    for (int i = t; i < 1024; i += 256) {
        int v = lh[i];
        if (v) atomicAdd(&binCount[i], v);
    }
}

// ---------------- exclusive scans: deg -> rowStart/rowFill, binCount -> binStart/binFill --------
#define SCAN_T 1024
__global__ void k_scan(const int* __restrict__ deg, int* __restrict__ rowStart,
                       int* __restrict__ rowFill, const int* __restrict__ binCount,
                       int* __restrict__ binStart, int* __restrict__ binFill) {
    __shared__ int sums[SCAN_T];
    int t = threadIdx.x;
    const int CHUNK = (N_ + SCAN_T - 1) / SCAN_T;  // 49
    int s0 = t * CHUNK;
    int local = 0;
    for (int i = 0; i < CHUNK; i++) {
        int idx = s0 + i;
        if (idx < N_) local += deg[idx];
    }
    sums[t] = local;
    __syncthreads();
    for (int off = 1; off < SCAN_T; off <<= 1) {
        int v = sums[t];
        int add = (t >= off) ? sums[t - off] : 0;
        __syncthreads();
        sums[t] = v + add;
        __syncthreads();
    }
    int run = (t == 0) ? 0 : sums[t - 1];
    for (int i = 0; i < CHUNK; i++) {
        int idx = s0 + i;
        if (idx < N_) {
            rowStart[idx] = run;
            rowFill[idx] = run;
            run += deg[idx];
        }
    }
    if (t == SCAN_T - 1) rowStart[N_] = sums[SCAN_T - 1];
    __syncthreads();
    // bins: exactly 1024
    int bv = binCount[t];
    sums[t] = bv;
    __syncthreads();
    for (int off = 1; off < SCAN_T; off <<= 1) {
        int v = sums[t];
        int add = (t >= off) ? sums[t - off] : 0;
        __syncthreads();
        sums[t] = v + add;
        __syncthreads();
    }
    int bp = (t == 0) ? 0 : sums[t - 1];
    binStart[t] = bp;
    binFill[t] = bp;
    if (t == SCAN_T - 1) binStart[SCAN_T] = sums[SCAN_T - 1];
}

// ---------------- scatter edges into CSR-by-dst and (gs,gd) buckets ----------------
__global__ void k_scatter(const int* __restrict__ ei, int* __restrict__ rowFill,
                          int* __restrict__ csr_src, int* __restrict__ binFill,
                          int* __restrict__ esrc, int* __restrict__ edst) {
    int e = blockIdx.x * 256 + threadIdx.x;
    if (e >= E_) return;
    int s = ei[e], d = ei[E_ + e];
    int p = atomicAdd(&rowFill[d], 1);
    csr_src[p] = s;
    int b = ((s * B_) / N_) * 32 + (d * B_) / N_;
    int q = atomicAdd(&binFill[b], 1);
    esrc[q] = s;
    edst[q] = d;
}

// ---------------- neigh[n] = mean over in-edges of x[src] (one wave per node) ------
__global__ __launch_bounds__(256) void k_agg(const float* __restrict__ x,
                                             const int* __restrict__ rowStart,
                                             const int* __restrict__ csr_src,
                                             float* __restrict__ neigh) {
    int node = blockIdx.x * 4 + (threadIdx.x >> 6);
    int lane = threadIdx.x & 63;
    if (node >= N_) return;
    int a = rowStart[node], bnd = rowStart[node + 1];
    float ax = 0.f, ay = 0.f;
    int j = a;
    for (; j + 1 < bnd; j += 2) {
        int s0 = csr_src[j], s1 = csr_src[j + 1];
        float2 v0 = *(const float2*)(x + s0 * 128 + lane * 2);
        float2 v1 = *(const float2*)(x + s1 * 128 + lane * 2);
        ax += v0.x + v1.x;
        ay += v0.y + v1.y;
    }
    if (j < bnd) {
        int s0 = csr_src[j];
        float2 v0 = *(const float2*)(x + s0 * 128 + lane * 2);
        ax += v0.x;
        ay += v0.y;
    }
    float inv = 1.0f / (float)max(bnd - a, 1);
    float2 o;
    o.x = ax * inv;
    o.y = ay * inv;
    *(float2*)(neigh + node * 128 + lane * 2) = o;
}

// ---------------- combine W_embed|W_pool into Wc[256][384], bias[384] ----------------
__global__ void k_prep(const float* __restrict__ We, const float* __restrict__ be,
                       const float* __restrict__ Wp, const float* __restrict__ bp,
                       float* __restrict__ Wc, float* __restrict__ bias) {
    int idx = blockIdx.x * 256 + threadIdx.x;
    if (idx < KTOT * JTOT) {
        int k = idx / JTOT, j = idx - k * JTOT;
        Wc[idx] = (j < 128) ? We[k * 128 + j] : Wp[k * 256 + (j - 128)];
    }
    if (idx < JTOT) bias[idx] = (idx < 128) ? be[idx] : bp[idx - 128];
}

// ---------------- fused GEMM: [x|neigh] (N x 256) @ Wc (256 x 384) ----------------
#define BM 64
#define BN 128
#define BK 32
__global__ __launch_bounds__(256) void k_gemm(const float* __restrict__ x,
                                              const float* __restrict__ neigh,
                                              const float* __restrict__ Wc,
                                              const float* __restrict__ bias,
                                              float* __restrict__ embed,
                                              float* __restrict__ plog) {
    __shared__ float As[BK][68];   // k-major, padded (stride 272B = 16B-aligned)
    __shared__ float Bs[BK][132];  // padded (stride 528B = 16B-aligned)
    int t = threadIdx.x;
    int row0 = blockIdx.x * BM;
    int col0 = blockIdx.y * BN;
    int tm = t >> 4, tn = t & 15;
    float acc[4][8] = {};
    for (int kt = 0; kt < KTOT; kt += BK) {
        const float* Asrc = (kt < 128) ? x : neigh;
        int kbase = kt & 127;
#pragma unroll
        for (int i = 0; i < 2; i++) {
            int lin = (i * 256 + t) * 4;  // 0..2047
            int m = lin >> 5;
            int k0 = lin & 31;
            int node = row0 + m;
            float4 v = {0.f, 0.f, 0.f, 0.f};
            if (node < N_) v = *(const float4*)(Asrc + node * 128 + kbase + k0);
            As[k0 + 0][m] = v.x;
            As[k0 + 1][m] = v.y;
            As[k0 + 2][m] = v.z;
            As[k0 + 3][m] = v.w;
        }
#pragma unroll
        for (int i = 0; i < 4; i++) {
            int lin = (i * 256 + t) * 4;  // 0..4095
            int k = lin >> 7;
            int n0 = lin & 127;
            float4 v = *(const float4*)(Wc + (kt + k) * JTOT + col0 + n0);
            *(float4*)&Bs[k][n0] = v;
        }
        __syncthreads();
#pragma unroll
        for (int kk = 0; kk < BK; kk++) {
            float a[4], b[8];
            *(float4*)a = *(const float4*)&As[kk][tm * 4];
            *(float4*)b = *(const float4*)&Bs[kk][tn * 8];
            *(float4*)(b + 4) = *(const float4*)&Bs[kk][tn * 8 + 4];
#pragma unroll
            for (int i = 0; i < 4; i++)
#pragma unroll
                for (int jj = 0; jj < 8; jj++) acc[i][jj] += a[i] * b[jj];
        }
        __syncthreads();
    }
#pragma unroll
    for (int i = 0; i < 4; i++) {
        int node = row0 + tm * 4 + i;
        if (node >= N_) continue;
#pragma unroll
        for (int jj = 0; jj < 8; jj++) {
            int j = col0 + tn * 8 + jj;
            float v = acc[i][jj] + bias[j];
            if (j < 128)
                embed[node * 128 + j] = v;
            else
                plog[node * 256 + (j - 128)] = v;
        }
    }
}

// ---------------- double softmax -> compact r8[N][8] ----------------
__global__ __launch_bounds__(256) void k_r(const float* __restrict__ plog,
                                           const int* __restrict__ batch,
                                           float* __restrict__ r8) {
    int node = blockIdx.x * 4 + (threadIdx.x >> 6);
    int lane = threadIdx.x & 63;
    if (node >= N_) return;
    float4 p = *(const float4*)(plog + node * 256 + lane * 4);
    float m = fmaxf(fmaxf(p.x, p.y), fmaxf(p.z, p.w));
    for (int off = 32; off; off >>= 1) m = fmaxf(m, __shfl_xor(m, off, 64));
    float s = expf(p.x - m) + expf(p.y - m) + expf(p.z - m) + expf(p.w - m);
    for (int off = 32; off; off >>= 1) s += __shfl_xor(s, off, 64);
    int g = batch[node];
    // first softmax value for this node's 8 cluster columns (lanes 0..7 active)
    float v = 0.f;
    if (lane < 8) v = expf(plog[node * 256 + g * 8 + lane] - m) / s;
    // second softmax over masked row: 8 group values + 248 zeros (exp(0)=1 each)
    float M2 = v;  // all v>0, so max over masked row = max over group
    for (int off = 4; off; off >>= 1) M2 = fmaxf(M2, __shfl_xor(M2, off, 64));
    float e = expf(v - M2);
    float Sg = e;
    for (int off = 4; off; off >>= 1) Sg += __shfl_xor(Sg, off, 64);
    float D2 = Sg + 248.0f * expf(-M2);            // full softmax denominator
    float r = e / (Sg + 1e-13f * D2);              // (e/D2) / (Sg/D2 + 1e-13)
    if (lane < 8) r8[node * 8 + lane] = r;
}

// ---------------- h = r^T @ embed, one workgroup per graph ----------------
__global__ __launch_bounds__(256) void k_h(const float* __restrict__ embed,
                                           const float* __restrict__ r8,
                                           float* __restrict__ out_h) {
    int g = blockIdx.x;
    int t = threadIdx.x;
    int o = t & 127, half = t >> 7;
    int n0 = (g * N_ + 31) >> 5;        // ceil(g*N/B)
    int n1 = ((g + 1) * N_ + 31) >> 5;  // ceil((g+1)*N/B)
    float a0 = 0.f, a1 = 0.f, a2 = 0.f, a3 = 0.f;
    for (int n = n0; n < n1; n++) {
        float e = embed[n * 128 + o];
        const float* rr = r8 + n * 8 + half;
        a0 += rr[0] * e;
        a1 += rr[2] * e;
        a2 += rr[4] * e;
        a3 += rr[6] * e;
    }
    out_h[(g * 8 + half + 0) * 128 + o] = a0;
    out_h[(g * 8 + half + 2) * 128 + o] = a1;
    out_h[(g * 8 + half + 4) * 128 + o] = a2;
    out_h[(g * 8 + half + 6) * 128 + o] = a3;
}

// ---------------- adj = sum over edges of outer(r8[s], r8[d]) per (gs,gd) bucket ---
__global__ __launch_bounds__(256) void k_adj(const int* __restrict__ binStart,
                                             const int* __restrict__ esrc,
                                             const int* __restrict__ edst,
                                             const float* __restrict__ r8,
                                             float* __restrict__ adj) {
    __shared__ float part[4][64];
    int bkt = blockIdx.x;  // 0..1023
    int w = threadIdx.x >> 6, lane = threadIdx.x & 63;
    int a = lane >> 3, bb = lane & 7;
    int s0 = binStart[bkt], s1 = binStart[bkt + 1];
    float acc = 0.f;
    for (int j = s0 + w; j < s1; j += 4) {
        int s = esrc[j], d = edst[j];
        acc += r8[s * 8 + a] * r8[d * 8 + bb];
    }
    part[w][lane] = acc;
    __syncthreads();
    if (w == 0) {
        float v = part[0][lane] + part[1][lane] + part[2][lane] + part[3][lane];
        int g1 = bkt >> 5, g2 = bkt & 31;
        adj[(g1 * 8 + a) * 256 + g2 * 8 + bb] = v;
    }
}

extern "C" void kernel_launch(void* const* d_in, const int* in_sizes, int n_in,
                              void* d_out, int out_size, void* d_ws, size_t ws_size,
                              hipStream_t stream) {
    const float* x = (const float*)d_in[0];
    const int* ei = (const int*)d_in[1];
    const int* batch = (const int*)d_in[2];
    const float* We = (const float*)d_in[3];
    const float* be = (const float*)d_in[4];
    const float* Wp = (const float*)d_in[5];
    const float* bp = (const float*)d_in[6];
    float* out = (float*)d_out;  // [adj 256*256 | h 256*128]

    char* w = (char*)d_ws;
    auto alloc = [&](size_t bytes) -> char* {
        char* p = w;
        w += (bytes + 255) & ~(size_t)255;
        return p;
    };
    float* neigh = (float*)alloc((size_t)N_ * 128 * 4);
    float* embed = (float*)alloc((size_t)N_ * 128 * 4);
    float* plog = (float*)alloc((size_t)N_ * 256 * 4);
    float* r8 = (float*)alloc((size_t)N_ * 8 * 4);
    float* Wc = (float*)alloc((size_t)KTOT * JTOT * 4);
    float* bias = (float*)alloc(JTOT * 4);
    int* deg = (int*)alloc((size_t)N_ * 4);
    int* rowStart = (int*)alloc((size_t)(N_ + 1) * 4);
    int* rowFill = (int*)alloc((size_t)N_ * 4);
    int* csr_src = (int*)alloc((size_t)E_ * 4);
    int* binCount = (int*)alloc(1024 * 4);
    int* binStart = (int*)alloc(1025 * 4);
    int* binFill = (int*)alloc(1024 * 4);
    int* esrc = (int*)alloc((size_t)E_ * 4);
    int* edst = (int*)alloc((size_t)E_ * 4);

    hipMemsetAsync(deg, 0, (size_t)N_ * 4, stream);
    hipMemsetAsync(binCount, 0, 1024 * 4, stream);

    k_hist<<<(E_ + 255) / 256, 256, 0, stream>>>(ei, deg, binCount);
    k_scan<<<1, SCAN_T, 0, stream>>>(deg, rowStart, rowFill, binCount, binStart, binFill);
    k_scatter<<<(E_ + 255) / 256, 256, 0, stream>>>(ei, rowFill, csr_src, binFill, esrc, edst);
    k_agg<<<(N_ + 3) / 4, 256, 0, stream>>>(x, rowStart, csr_src, neigh);
    k_prep<<<(KTOT * JTOT + 255) / 256, 256, 0, stream>>>(We, be, Wp, bp, Wc, bias);
    dim3 gg((N_ + BM - 1) / BM, JTOT / BN);
    k_gemm<<<gg, 256, 0, stream>>>(x, neigh, Wc, bias, embed, plog);
    k_r<<<(N_ + 3) / 4, 256, 0, stream>>>(plog, batch, r8);
    k_h<<<32, 256, 0, stream>>>(embed, r8, out + 256 * 256);
    k_adj<<<1024, 256, 0, stream>>>(binStart, esrc, edst, r8, out);
}

// Round 2
// 806.829 us; speedup vs baseline: 1.4823x; 1.4823x over previous
//
#include <hip/hip_runtime.h>
#include <hip/hip_bf16.h>

#define N_ 50000
#define E_ 800000
#define IN_ 128
#define OUT_ 128
#define ASSIGN_ 256
#define B_ 32
#define KTOT 256     // 2*IN
#define JTOT 384     // OUT + ASSIGN
#define HCHUNK 16    // chunks per graph for k_h_part

// ---------------- histogram: deg[dst]++ and (gs,gd) bucket counts ----------------
__global__ void k_hist(const int* __restrict__ ei, int* __restrict__ deg,
                       int* __restrict__ binCount) {
    __shared__ int lh[1024];
    int t = threadIdx.x;
    for (int i = t; i < 1024; i += 256) lh[i] = 0;
    __syncthreads();
    int e = blockIdx.x * 256 + t;
    if (e < E_) {
        int s = ei[e], d = ei[E_ + e];
        atomicAdd(&deg[d], 1);
        int gs = (s * B_) / N_, gd = (d * B_) / N_;
        atomicAdd(&lh[gs * 32 + gd], 1);
    }
    __syncthreads();
    for (int i = t; i < 1024; i += 256) {
        int v = lh[i];
        if (v) atomicAdd(&binCount[i], v);
    }
}

// ---------------- exclusive scans: deg -> rowStart/rowFill, binCount -> binStart/binFill --------
#define SCAN_T 1024
__global__ void k_scan(const int* __restrict__ deg, int* __restrict__ rowStart,
                       int* __restrict__ rowFill, const int* __restrict__ binCount,
                       int* __restrict__ binStart, int* __restrict__ binFill) {
    __shared__ int sums[SCAN_T];
    int t = threadIdx.x;
    const int CHUNK = (N_ + SCAN_T - 1) / SCAN_T;  // 49
    int s0 = t * CHUNK;
    int local = 0;
    for (int i = 0; i < CHUNK; i++) {
        int idx = s0 + i;
        if (idx < N_) local += deg[idx];
    }
    sums[t] = local;
    __syncthreads();
    for (int off = 1; off < SCAN_T; off <<= 1) {
        int v = sums[t];
        int add = (t >= off) ? sums[t - off] : 0;
        __syncthreads();
        sums[t] = v + add;
        __syncthreads();
    }
    int run = (t == 0) ? 0 : sums[t - 1];
    for (int i = 0; i < CHUNK; i++) {
        int idx = s0 + i;
        if (idx < N_) {
            rowStart[idx] = run;
            rowFill[idx] = run;
            run += deg[idx];
        }
    }
    if (t == SCAN_T - 1) rowStart[N_] = sums[SCAN_T - 1];
    __syncthreads();
    // bins: exactly 1024
    int bv = binCount[t];
    sums[t] = bv;
    __syncthreads();
    for (int off = 1; off < SCAN_T; off <<= 1) {
        int v = sums[t];
        int add = (t >= off) ? sums[t - off] : 0;
        __syncthreads();
        sums[t] = v + add;
        __syncthreads();
    }
    int bp = (t == 0) ? 0 : sums[t - 1];
    binStart[t] = bp;
    binFill[t] = bp;
    if (t == SCAN_T - 1) binStart[SCAN_T] = sums[SCAN_T - 1];
}

// ---------------- scatter edges into CSR-by-dst and (gs,gd) buckets ----------------
__global__ void k_scatter(const int* __restrict__ ei, int* __restrict__ rowFill,
                          int* __restrict__ csr_src, int* __restrict__ binFill,
                          int* __restrict__ esrc, int* __restrict__ edst) {
    int e = blockIdx.x * 256 + threadIdx.x;
    if (e >= E_) return;
    int s = ei[e], d = ei[E_ + e];
    int p = atomicAdd(&rowFill[d], 1);
    csr_src[p] = s;
    int b = ((s * B_) / N_) * 32 + (d * B_) / N_;
    int q = atomicAdd(&binFill[b], 1);
    esrc[q] = s;
    edst[q] = d;
}

// ---------------- neigh[n] = mean over in-edges of x[src] (one wave per node) ------
__global__ __launch_bounds__(256) void k_agg(const float* __restrict__ x,
                                             const int* __restrict__ rowStart,
                                             const int* __restrict__ csr_src,
                                             float* __restrict__ neigh) {
    int node = blockIdx.x * 4 + (threadIdx.x >> 6);
    int lane = threadIdx.x & 63;
    if (node >= N_) return;
    int a = rowStart[node], bnd = rowStart[node + 1];
    float ax = 0.f, ay = 0.f;
    int j = a;
    for (; j + 1 < bnd; j += 2) {
        int s0 = csr_src[j], s1 = csr_src[j + 1];
        float2 v0 = *(const float2*)(x + s0 * 128 + lane * 2);
        float2 v1 = *(const float2*)(x + s1 * 128 + lane * 2);
        ax += v0.x + v1.x;
        ay += v0.y + v1.y;
    }
    if (j < bnd) {
        int s0 = csr_src[j];
        float2 v0 = *(const float2*)(x + s0 * 128 + lane * 2);
        ax += v0.x;
        ay += v0.y;
    }
    float inv = 1.0f / (float)max(bnd - a, 1);
    float2 o;
    o.x = ax * inv;
    o.y = ay * inv;
    *(float2*)(neigh + node * 128 + lane * 2) = o;
}

// ---------------- combine W_embed|W_pool into Wc[256][384], bias[384] ----------------
__global__ void k_prep(const float* __restrict__ We, const float* __restrict__ be,
                       const float* __restrict__ Wp, const float* __restrict__ bp,
                       float* __restrict__ Wc, float* __restrict__ bias) {
    int idx = blockIdx.x * 256 + threadIdx.x;
    if (idx < KTOT * JTOT) {
        int k = idx / JTOT, j = idx - k * JTOT;
        Wc[idx] = (j < 128) ? We[k * 128 + j] : Wp[k * 256 + (j - 128)];
    }
    if (idx < JTOT) bias[idx] = (idx < 128) ? be[idx] : bp[idx - 128];
}

// ---------------- fused GEMM: [x|neigh] (N x 256) @ Wc (256 x 384) ----------------
#define BM 64
#define BN 128
#define BK 32
__global__ __launch_bounds__(256) void k_gemm(const float* __restrict__ x,
                                              const float* __restrict__ neigh,
                                              const float* __restrict__ Wc,
                                              const float* __restrict__ bias,
                                              float* __restrict__ embed,
                                              float* __restrict__ plog) {
    __shared__ float As[BK][68];   // k-major, padded (stride 272B = 16B-aligned)
    __shared__ float Bs[BK][132];  // padded (stride 528B = 16B-aligned)
    int t = threadIdx.x;
    int row0 = blockIdx.x * BM;
    int col0 = blockIdx.y * BN;
    int tm = t >> 4, tn = t & 15;
    float acc[4][8] = {};
    for (int kt = 0; kt < KTOT; kt += BK) {
        const float* Asrc = (kt < 128) ? x : neigh;
        int kbase = kt & 127;
#pragma unroll
        for (int i = 0; i < 2; i++) {
            int lin = (i * 256 + t) * 4;  // 0..2047
            int m = lin >> 5;
            int k0 = lin & 31;
            int node = row0 + m;
            float4 v = {0.f, 0.f, 0.f, 0.f};
            if (node < N_) v = *(const float4*)(Asrc + node * 128 + kbase + k0);
            As[k0 + 0][m] = v.x;
            As[k0 + 1][m] = v.y;
            As[k0 + 2][m] = v.z;
            As[k0 + 3][m] = v.w;
        }
#pragma unroll
        for (int i = 0; i < 4; i++) {
            int lin = (i * 256 + t) * 4;  // 0..4095
            int k = lin >> 7;
            int n0 = lin & 127;
            float4 v = *(const float4*)(Wc + (kt + k) * JTOT + col0 + n0);
            *(float4*)&Bs[k][n0] = v;
        }
        __syncthreads();
#pragma unroll
        for (int kk = 0; kk < BK; kk++) {
            float a[4], b[8];
            *(float4*)a = *(const float4*)&As[kk][tm * 4];
            *(float4*)b = *(const float4*)&Bs[kk][tn * 8];
            *(float4*)(b + 4) = *(const float4*)&Bs[kk][tn * 8 + 4];
#pragma unroll
            for (int i = 0; i < 4; i++)
#pragma unroll
                for (int jj = 0; jj < 8; jj++) acc[i][jj] += a[i] * b[jj];
        }
        __syncthreads();
    }
#pragma unroll
    for (int i = 0; i < 4; i++) {
        int node = row0 + tm * 4 + i;
        if (node >= N_) continue;
#pragma unroll
        for (int jj = 0; jj < 8; jj++) {
            int j = col0 + tn * 8 + jj;
            float v = acc[i][jj] + bias[j];
            if (j < 128)
                embed[node * 128 + j] = v;
            else
                plog[node * 256 + (j - 128)] = v;
        }
    }
}

// ---------------- double softmax -> compact r8[N][8] ----------------
__global__ __launch_bounds__(256) void k_r(const float* __restrict__ plog,
                                           const int* __restrict__ batch,
                                           float* __restrict__ r8) {
    int node = blockIdx.x * 4 + (threadIdx.x >> 6);
    int lane = threadIdx.x & 63;
    if (node >= N_) return;
    float4 p = *(const float4*)(plog + node * 256 + lane * 4);
    float m = fmaxf(fmaxf(p.x, p.y), fmaxf(p.z, p.w));
    for (int off = 32; off; off >>= 1) m = fmaxf(m, __shfl_xor(m, off, 64));
    float s = expf(p.x - m) + expf(p.y - m) + expf(p.z - m) + expf(p.w - m);
    for (int off = 32; off; off >>= 1) s += __shfl_xor(s, off, 64);
    int g = batch[node];
    // first softmax value for this node's 8 cluster columns (lanes 0..7 active)
    float v = 0.f;
    if (lane < 8) v = expf(plog[node * 256 + g * 8 + lane] - m) / s;
    // second softmax over masked row: 8 group values + 248 zeros (exp(0)=1 each)
    float M2 = v;  // all v>0, so max over masked row = max over group
    for (int off = 4; off; off >>= 1) M2 = fmaxf(M2, __shfl_xor(M2, off, 64));
    float e = expf(v - M2);
    float Sg = e;
    for (int off = 4; off; off >>= 1) Sg += __shfl_xor(Sg, off, 64);
    float D2 = Sg + 248.0f * expf(-M2);            // full softmax denominator
    float r = e / (Sg + 1e-13f * D2);              // (e/D2) / (Sg/D2 + 1e-13)
    if (lane < 8) r8[node * 8 + lane] = r;
}

// ---------------- h partials: grid (32 graphs x HCHUNK chunks) ----------------
// partH[(g*HCHUNK + c)][cl*128 + o] = sum over chunk nodes of r8[n][cl]*embed[n][o]
__global__ __launch_bounds__(256) void k_h_part(const float* __restrict__ embed,
                                                const float* __restrict__ r8,
                                                float* __restrict__ partH) {
    int g = blockIdx.x;
    int c = blockIdx.y;
    int t = threadIdx.x;
    int o = t & 127, half = t >> 7;  // half in {0,1}: clusters half, half+2, half+4, half+6
    int n0g = (g * N_ + 31) >> 5;
    int n1g = ((g + 1) * N_ + 31) >> 5;
    int len = n1g - n0g;
    int a = n0g + (len * c) / HCHUNK;
    int b = n0g + (len * (c + 1)) / HCHUNK;
    float a0 = 0.f, a1 = 0.f, a2 = 0.f, a3 = 0.f;
#pragma unroll 4
    for (int n = a; n < b; n++) {
        float e = embed[n * 128 + o];
        const float* rr = r8 + n * 8 + half;
        a0 += rr[0] * e;
        a1 += rr[2] * e;
        a2 += rr[4] * e;
        a3 += rr[6] * e;
    }
    float* pb = partH + (g * HCHUNK + c) * 1024;
    pb[(half + 0) * 128 + o] = a0;
    pb[(half + 2) * 128 + o] = a1;
    pb[(half + 4) * 128 + o] = a2;
    pb[(half + 6) * 128 + o] = a3;
}

// ---------------- h reduce: sum HCHUNK partials per output element ----------------
__global__ __launch_bounds__(256) void k_h_red(const float* __restrict__ partH,
                                               float* __restrict__ out_h) {
    int idx = blockIdx.x * 256 + threadIdx.x;  // 0..32767
    if (idx >= 256 * 128) return;
    int g = idx >> 10;          // graph
    int local = idx & 1023;     // cl*128+o within graph block
    float s = 0.f;
#pragma unroll
    for (int c = 0; c < HCHUNK; c++) s += partH[(g * HCHUNK + c) * 1024 + local];
    out_h[idx] = s;
}

// ---------------- adj = sum over edges of outer(r8[s], r8[d]) per (gs,gd) bucket ---
__global__ __launch_bounds__(256) void k_adj(const int* __restrict__ binStart,
                                             const int* __restrict__ esrc,
                                             const int* __restrict__ edst,
                                             const float* __restrict__ r8,
                                             float* __restrict__ adj) {
    __shared__ float part[4][64];
    int bkt = blockIdx.x;  // 0..1023
    int w = threadIdx.x >> 6, lane = threadIdx.x & 63;
    int a = lane >> 3, bb = lane & 7;
    int s0 = binStart[bkt], s1 = binStart[bkt + 1];
    float acc = 0.f;
    for (int j = s0 + w; j < s1; j += 4) {
        int s = esrc[j], d = edst[j];
        acc += r8[s * 8 + a] * r8[d * 8 + bb];
    }
    part[w][lane] = acc;
    __syncthreads();
    if (w == 0) {
        float v = part[0][lane] + part[1][lane] + part[2][lane] + part[3][lane];
        int g1 = bkt >> 5, g2 = bkt & 31;
        adj[(g1 * 8 + a) * 256 + g2 * 8 + bb] = v;
    }
}

extern "C" void kernel_launch(void* const* d_in, const int* in_sizes, int n_in,
                              void* d_out, int out_size, void* d_ws, size_t ws_size,
                              hipStream_t stream) {
    const float* x = (const float*)d_in[0];
    const int* ei = (const int*)d_in[1];
    const int* batch = (const int*)d_in[2];
    const float* We = (const float*)d_in[3];
    const float* be = (const float*)d_in[4];
    const float* Wp = (const float*)d_in[5];
    const float* bp = (const float*)d_in[6];
    float* out = (float*)d_out;  // [adj 256*256 | h 256*128]

    char* w = (char*)d_ws;
    auto alloc = [&](size_t bytes) -> char* {
        char* p = w;
        w += (bytes + 255) & ~(size_t)255;
        return p;
    };
    float* neigh = (float*)alloc((size_t)N_ * 128 * 4);
    float* embed = (float*)alloc((size_t)N_ * 128 * 4);
    float* plog = (float*)alloc((size_t)N_ * 256 * 4);
    float* r8 = (float*)alloc((size_t)N_ * 8 * 4);
    float* Wc = (float*)alloc((size_t)KTOT * JTOT * 4);
    float* bias = (float*)alloc(JTOT * 4);
    int* deg = (int*)alloc((size_t)N_ * 4);
    int* rowStart = (int*)alloc((size_t)(N_ + 1) * 4);
    int* rowFill = (int*)alloc((size_t)N_ * 4);
    int* csr_src = (int*)alloc((size_t)E_ * 4);
    int* binCount = (int*)alloc(1024 * 4);
    int* binStart = (int*)alloc(1025 * 4);
    int* binFill = (int*)alloc(1024 * 4);
    int* esrc = (int*)alloc((size_t)E_ * 4);
    int* edst = (int*)alloc((size_t)E_ * 4);
    float* partH = (float*)alloc((size_t)B_ * HCHUNK * 1024 * 4);

    hipMemsetAsync(deg, 0, (size_t)N_ * 4, stream);
    hipMemsetAsync(binCount, 0, 1024 * 4, stream);

    k_hist<<<(E_ + 255) / 256, 256, 0, stream>>>(ei, deg, binCount);
    k_scan<<<1, SCAN_T, 0, stream>>>(deg, rowStart, rowFill, binCount, binStart, binFill);
    k_scatter<<<(E_ + 255) / 256, 256, 0, stream>>>(ei, rowFill, csr_src, binFill, esrc, edst);
    k_agg<<<(N_ + 3) / 4, 256, 0, stream>>>(x, rowStart, csr_src, neigh);
    k_prep<<<(KTOT * JTOT + 255) / 256, 256, 0, stream>>>(We, be, Wp, bp, Wc, bias);
    dim3 gg((N_ + BM - 1) / BM, JTOT / BN);
    k_gemm<<<gg, 256, 0, stream>>>(x, neigh, Wc, bias, embed, plog);
    k_r<<<(N_ + 3) / 4, 256, 0, stream>>>(plog, batch, r8);
    dim3 hg(B_, HCHUNK);
    k_h_part<<<hg, 256, 0, stream>>>(embed, r8, partH);
    k_h_red<<<(256 * 128 + 255) / 256, 256, 0, stream>>>(partH, out + 256 * 256);
    k_adj<<<1024, 256, 0, stream>>>(binStart, esrc, edst, r8, out);
}

// Round 3
// 655.270 us; speedup vs baseline: 1.8252x; 1.2313x over previous
//
#include <hip/hip_runtime.h>
#include <hip/hip_bf16.h>

#define N_ 50000
#define E_ 800000
#define IN_ 128
#define OUT_ 128
#define ASSIGN_ 256
#define B_ 32
#define KTOT 256     // 2*IN
#define JTOT 384     // OUT + ASSIGN
#define HCHUNK 16    // chunks per graph for k_h_part
#define ACHUNK 16    // chunks per graph for k_adj

// ---------------- histogram: deg[dst]++ ----------------
__global__ void k_hist(const int* __restrict__ ei, int* __restrict__ deg) {
    int e = blockIdx.x * 256 + threadIdx.x;
    if (e < E_) atomicAdd(&deg[ei[E_ + e]], 1);
}

// ---------------- exclusive scan: deg -> rowStart/rowFill ----------------
#define SCAN_T 1024
__global__ void k_scan(const int* __restrict__ deg, int* __restrict__ rowStart,
                       int* __restrict__ rowFill) {
    __shared__ int sums[SCAN_T];
    int t = threadIdx.x;
    const int CHUNK = (N_ + SCAN_T - 1) / SCAN_T;  // 49
    int s0 = t * CHUNK;
    int local = 0;
    for (int i = 0; i < CHUNK; i++) {
        int idx = s0 + i;
        if (idx < N_) local += deg[idx];
    }
    sums[t] = local;
    __syncthreads();
    for (int off = 1; off < SCAN_T; off <<= 1) {
        int v = sums[t];
        int add = (t >= off) ? sums[t - off] : 0;
        __syncthreads();
        sums[t] = v + add;
        __syncthreads();
    }
    int run = (t == 0) ? 0 : sums[t - 1];
    for (int i = 0; i < CHUNK; i++) {
        int idx = s0 + i;
        if (idx < N_) {
            rowStart[idx] = run;
            rowFill[idx] = run;
            run += deg[idx];
        }
    }
    if (t == SCAN_T - 1) rowStart[N_] = sums[SCAN_T - 1];
}

// ---------------- scatter edges into CSR-by-dst ----------------
__global__ void k_scatter(const int* __restrict__ ei, int* __restrict__ rowFill,
                          int* __restrict__ csr_src) {
    int e = blockIdx.x * 256 + threadIdx.x;
    if (e >= E_) return;
    int s = ei[e], d = ei[E_ + e];
    int p = atomicAdd(&rowFill[d], 1);
    csr_src[p] = s;
}

// ---------------- neigh[n] = mean over in-edges of x[src] (one wave per node) ------
__global__ __launch_bounds__(256) void k_agg(const float* __restrict__ x,
                                             const int* __restrict__ rowStart,
                                             const int* __restrict__ csr_src,
                                             float* __restrict__ neigh) {
    int node = blockIdx.x * 4 + (threadIdx.x >> 6);
    int lane = threadIdx.x & 63;
    if (node >= N_) return;
    int a = rowStart[node], bnd = rowStart[node + 1];
    float ax = 0.f, ay = 0.f;
    int j = a;
    for (; j + 1 < bnd; j += 2) {
        int s0 = csr_src[j], s1 = csr_src[j + 1];
        float2 v0 = *(const float2*)(x + s0 * 128 + lane * 2);
        float2 v1 = *(const float2*)(x + s1 * 128 + lane * 2);
        ax += v0.x + v1.x;
        ay += v0.y + v1.y;
    }
    if (j < bnd) {
        int s0 = csr_src[j];
        float2 v0 = *(const float2*)(x + s0 * 128 + lane * 2);
        ax += v0.x;
        ay += v0.y;
    }
    float inv = 1.0f / (float)max(bnd - a, 1);
    float2 o;
    o.x = ax * inv;
    o.y = ay * inv;
    *(float2*)(neigh + node * 128 + lane * 2) = o;
}

// ---------------- combine W_embed|W_pool into Wc[256][384], bias[384] ----------------
__global__ void k_prep(const float* __restrict__ We, const float* __restrict__ be,
                       const float* __restrict__ Wp, const float* __restrict__ bp,
                       float* __restrict__ Wc, float* __restrict__ bias) {
    int idx = blockIdx.x * 256 + threadIdx.x;
    if (idx < KTOT * JTOT) {
        int k = idx / JTOT, j = idx - k * JTOT;
        Wc[idx] = (j < 128) ? We[k * 128 + j] : Wp[k * 256 + (j - 128)];
    }
    if (idx < JTOT) bias[idx] = (idx < 128) ? be[idx] : bp[idx - 128];
}

// ---------------- fused GEMM: [x|neigh] (N x 256) @ Wc (256 x 384) ----------------
#define BM 64
#define BN 128
#define BK 32
__global__ __launch_bounds__(256) void k_gemm(const float* __restrict__ x,
                                              const float* __restrict__ neigh,
                                              const float* __restrict__ Wc,
                                              const float* __restrict__ bias,
                                              float* __restrict__ embed,
                                              float* __restrict__ plog) {
    __shared__ float As[BK][68];   // k-major, padded
    __shared__ float Bs[BK][132];  // padded
    int t = threadIdx.x;
    int row0 = blockIdx.x * BM;
    int col0 = blockIdx.y * BN;
    int tm = t >> 4, tn = t & 15;
    float acc[4][8] = {};
    for (int kt = 0; kt < KTOT; kt += BK) {
        const float* Asrc = (kt < 128) ? x : neigh;
        int kbase = kt & 127;
#pragma unroll
        for (int i = 0; i < 2; i++) {
            int lin = (i * 256 + t) * 4;  // 0..2047
            int m = lin >> 5;
            int k0 = lin & 31;
            int node = row0 + m;
            float4 v = {0.f, 0.f, 0.f, 0.f};
            if (node < N_) v = *(const float4*)(Asrc + node * 128 + kbase + k0);
            As[k0 + 0][m] = v.x;
            As[k0 + 1][m] = v.y;
            As[k0 + 2][m] = v.z;
            As[k0 + 3][m] = v.w;
        }
#pragma unroll
        for (int i = 0; i < 4; i++) {
            int lin = (i * 256 + t) * 4;  // 0..4095
            int k = lin >> 7;
            int n0 = lin & 127;
            float4 v = *(const float4*)(Wc + (kt + k) * JTOT + col0 + n0);
            *(float4*)&Bs[k][n0] = v;
        }
        __syncthreads();
#pragma unroll
        for (int kk = 0; kk < BK; kk++) {
            float a[4], b[8];
            *(float4*)a = *(const float4*)&As[kk][tm * 4];
            *(float4*)b = *(const float4*)&Bs[kk][tn * 8];
            *(float4*)(b + 4) = *(const float4*)&Bs[kk][tn * 8 + 4];
#pragma unroll
            for (int i = 0; i < 4; i++)
#pragma unroll
                for (int jj = 0; jj < 8; jj++) acc[i][jj] += a[i] * b[jj];
        }
        __syncthreads();
    }
#pragma unroll
    for (int i = 0; i < 4; i++) {
        int node = row0 + tm * 4 + i;
        if (node >= N_) continue;
#pragma unroll
        for (int jj = 0; jj < 8; jj++) {
            int j = col0 + tn * 8 + jj;
            float v = acc[i][jj] + bias[j];
            if (j < 128)
                embed[node * 128 + j] = v;
            else
                plog[node * 256 + (j - 128)] = v;
        }
    }
}

// ---------------- double softmax -> compact r8[N][8] ----------------
__global__ __launch_bounds__(256) void k_r(const float* __restrict__ plog,
                                           const int* __restrict__ batch,
                                           float* __restrict__ r8) {
    int node = blockIdx.x * 4 + (threadIdx.x >> 6);
    int lane = threadIdx.x & 63;
    if (node >= N_) return;
    float4 p = *(const float4*)(plog + node * 256 + lane * 4);
    float m = fmaxf(fmaxf(p.x, p.y), fmaxf(p.z, p.w));
    for (int off = 32; off; off >>= 1) m = fmaxf(m, __shfl_xor(m, off, 64));
    float s = expf(p.x - m) + expf(p.y - m) + expf(p.z - m) + expf(p.w - m);
    for (int off = 32; off; off >>= 1) s += __shfl_xor(s, off, 64);
    int g = batch[node];
    float v = 0.f;
    if (lane < 8) v = expf(plog[node * 256 + g * 8 + lane] - m) / s;
    float M2 = v;
    for (int off = 4; off; off >>= 1) M2 = fmaxf(M2, __shfl_xor(M2, off, 64));
    float e = expf(v - M2);
    float Sg = e;
    for (int off = 4; off; off >>= 1) Sg += __shfl_xor(Sg, off, 64);
    float D2 = Sg + 248.0f * expf(-M2);
    float r = e / (Sg + 1e-13f * D2);
    if (lane < 8) r8[node * 8 + lane] = r;
}

// ---------------- h partials: grid (32 graphs x HCHUNK chunks) ----------------
__global__ __launch_bounds__(256) void k_h_part(const float* __restrict__ embed,
                                                const float* __restrict__ r8,
                                                float* __restrict__ partH) {
    int g = blockIdx.x;
    int c = blockIdx.y;
    int t = threadIdx.x;
    int o = t & 127, half = t >> 7;
    int n0g = (g * N_ + 31) >> 5;
    int n1g = ((g + 1) * N_ + 31) >> 5;
    int len = n1g - n0g;
    int a = n0g + (len * c) / HCHUNK;
    int b = n0g + (len * (c + 1)) / HCHUNK;
    float a0 = 0.f, a1 = 0.f, a2 = 0.f, a3 = 0.f;
#pragma unroll 4
    for (int n = a; n < b; n++) {
        float e = embed[n * 128 + o];
        const float* rr = r8 + n * 8 + half;
        a0 += rr[0] * e;
        a1 += rr[2] * e;
        a2 += rr[4] * e;
        a3 += rr[6] * e;
    }
    float* pb = partH + (g * HCHUNK + c) * 1024;
    pb[(half + 0) * 128 + o] = a0;
    pb[(half + 2) * 128 + o] = a1;
    pb[(half + 4) * 128 + o] = a2;
    pb[(half + 6) * 128 + o] = a3;
}

// ---------------- h reduce ----------------
__global__ __launch_bounds__(256) void k_h_red(const float* __restrict__ partH,
                                               float* __restrict__ out_h) {
    int idx = blockIdx.x * 256 + threadIdx.x;  // 0..32767
    if (idx >= 256 * 128) return;
    int g = idx >> 10;
    int local = idx & 1023;
    float s = 0.f;
#pragma unroll
    for (int c = 0; c < HCHUNK; c++) s += partH[(g * HCHUNK + c) * 1024 + local];
    out_h[idx] = s;
}

// ---------------- adj partials from CSR: grid (32 gd x ACHUNK chunks) ----------------
// For dst nodes of graph gd in this chunk, for each in-edge (s -> n):
//   lacc[wave][gs*64 + a*8 + b] += r8[s][a] * r8[n][b]   (lane = a*8+b)
__global__ __launch_bounds__(256) void k_adj(const int* __restrict__ rowStart,
                                             const int* __restrict__ csr_src,
                                             const float* __restrict__ r8,
                                             float* __restrict__ partAdj) {
    __shared__ float lacc[4][2048];
    int gd = blockIdx.x;
    int c = blockIdx.y;
    int t = threadIdx.x;
    int w = t >> 6, lane = t & 63;
    int a = lane >> 3, b = lane & 7;
    for (int i = t; i < 4 * 2048; i += 256) ((float*)lacc)[i] = 0.f;
    __syncthreads();
    int n0g = (gd * N_ + 31) >> 5;
    int n1g = ((gd + 1) * N_ + 31) >> 5;
    int len = n1g - n0g;
    int na = n0g + (len * c) / ACHUNK;
    int nb = n0g + (len * (c + 1)) / ACHUNK;
    for (int n = na + w; n < nb; n += 4) {
        float rd = r8[n * 8 + b];  // broadcast across the 8 a-groups
        int j0 = rowStart[n], j1 = rowStart[n + 1];
        for (int j = j0; j < j1; j++) {
            int s = csr_src[j];          // uniform across wave
            int gs = (s * B_) / N_;
            float v = r8[s * 8 + a] * rd;
            lacc[w][gs * 64 + lane] += v;
        }
    }
    __syncthreads();
    float* pb = partAdj + (gd * ACHUNK + c) * 2048;
    for (int i = t; i < 2048; i += 256)
        pb[i] = lacc[0][i] + lacc[1][i] + lacc[2][i] + lacc[3][i];
}

// ---------------- adj reduce: 256x256 outputs, sum ACHUNK partials ----------------
__global__ __launch_bounds__(256) void k_adj_red(const float* __restrict__ partAdj,
                                                 float* __restrict__ adj) {
    int o = blockIdx.x * 256 + threadIdx.x;  // 0..65535
    if (o >= 256 * 256) return;
    int row = o >> 8, col = o & 255;
    int gs = row >> 3, a = row & 7;
    int gd = col >> 3, b = col & 7;
    int li = gs * 64 + a * 8 + b;
    float s = 0.f;
#pragma unroll
    for (int c = 0; c < ACHUNK; c++) s += partAdj[(gd * ACHUNK + c) * 2048 + li];
    adj[o] = s;
}

extern "C" void kernel_launch(void* const* d_in, const int* in_sizes, int n_in,
                              void* d_out, int out_size, void* d_ws, size_t ws_size,
                              hipStream_t stream) {
    const float* x = (const float*)d_in[0];
    const int* ei = (const int*)d_in[1];
    const int* batch = (const int*)d_in[2];
    const float* We = (const float*)d_in[3];
    const float* be = (const float*)d_in[4];
    const float* Wp = (const float*)d_in[5];
    const float* bp = (const float*)d_in[6];
    float* out = (float*)d_out;  // [adj 256*256 | h 256*128]

    char* w = (char*)d_ws;
    auto alloc = [&](size_t bytes) -> char* {
        char* p = w;
        w += (bytes + 255) & ~(size_t)255;
        return p;
    };
    float* neigh = (float*)alloc((size_t)N_ * 128 * 4);
    float* embed = (float*)alloc((size_t)N_ * 128 * 4);
    float* plog = (float*)alloc((size_t)N_ * 256 * 4);
    float* r8 = (float*)alloc((size_t)N_ * 8 * 4);
    float* Wc = (float*)alloc((size_t)KTOT * JTOT * 4);
    float* bias = (float*)alloc(JTOT * 4);
    int* deg = (int*)alloc((size_t)N_ * 4);
    int* rowStart = (int*)alloc((size_t)(N_ + 1) * 4);
    int* rowFill = (int*)alloc((size_t)N_ * 4);
    int* csr_src = (int*)alloc((size_t)E_ * 4);
    float* partH = (float*)alloc((size_t)B_ * HCHUNK * 1024 * 4);
    float* partAdj = (float*)alloc((size_t)B_ * ACHUNK * 2048 * 4);

    hipMemsetAsync(deg, 0, (size_t)N_ * 4, stream);

    k_hist<<<(E_ + 255) / 256, 256, 0, stream>>>(ei, deg);
    k_scan<<<1, SCAN_T, 0, stream>>>(deg, rowStart, rowFill);
    k_scatter<<<(E_ + 255) / 256, 256, 0, stream>>>(ei, rowFill, csr_src);
    k_agg<<<(N_ + 3) / 4, 256, 0, stream>>>(x, rowStart, csr_src, neigh);
    k_prep<<<(KTOT * JTOT + 255) / 256, 256, 0, stream>>>(We, be, Wp, bp, Wc, bias);
    dim3 gg((N_ + BM - 1) / BM, JTOT / BN);
    k_gemm<<<gg, 256, 0, stream>>>(x, neigh, Wc, bias, embed, plog);
    k_r<<<(N_ + 3) / 4, 256, 0, stream>>>(plog, batch, r8);
    dim3 hg(B_, HCHUNK);
    k_h_part<<<hg, 256, 0, stream>>>(embed, r8, partH);
    k_h_red<<<(256 * 128 + 255) / 256, 256, 0, stream>>>(partH, out + 256 * 256);
    dim3 ag(B_, ACHUNK);
    k_adj<<<ag, 256, 0, stream>>>(rowStart, csr_src, r8, partAdj);
    k_adj_red<<<(256 * 256 + 255) / 256, 256, 0, stream>>>(partAdj, out);
}

// Round 5
// 576.611 us; speedup vs baseline: 2.0742x; 1.1364x over previous
//
#include <hip/hip_runtime.h>
#include <hip/hip_bf16.h>

#define N_ 50000
#define E_ 800000
#define IN_ 128
#define OUT_ 128
#define ASSIGN_ 256
#define B_ 32
#define KTOT 256     // 2*IN
#define JTOT 384     // OUT + ASSIGN
#define HCHUNK 16
#define ACHUNK 16

typedef __attribute__((ext_vector_type(8))) short short8;
typedef __attribute__((ext_vector_type(4))) float f32x4;
typedef __attribute__((ext_vector_type(4))) unsigned short ushort4v;
typedef __attribute__((ext_vector_type(2))) unsigned short ushort2v;

struct HL { unsigned short h, l; };

__device__ inline unsigned short f2bf(float v) {
    union { float f; unsigned u; } a;
    a.f = v;
    unsigned r = a.u + 0x7fff + ((a.u >> 16) & 1);  // RNE
    return (unsigned short)(r >> 16);
}
__device__ inline float bf2f(unsigned short b) {
    union { unsigned u; float f; } a;
    a.u = ((unsigned)b) << 16;
    return a.f;
}
__device__ inline HL split2(float v) {
    HL r;
    r.h = f2bf(v);
    r.l = f2bf(v - bf2f(r.h));
    return r;
}

// ---------------- histogram: deg[dst]++ ----------------
__global__ void k_hist(const int* __restrict__ ei, int* __restrict__ deg) {
    int e = blockIdx.x * 256 + threadIdx.x;
    if (e < E_) atomicAdd(&deg[ei[E_ + e]], 1);
}

// ---------------- exclusive scan: deg -> rowStart/rowFill ----------------
#define SCAN_T 1024
__global__ void k_scan(const int* __restrict__ deg, int* __restrict__ rowStart,
                       int* __restrict__ rowFill) {
    __shared__ int sums[SCAN_T];
    int t = threadIdx.x;
    const int CHUNK = (N_ + SCAN_T - 1) / SCAN_T;  // 49
    int s0 = t * CHUNK;
    int local = 0;
    for (int i = 0; i < CHUNK; i++) {
        int idx = s0 + i;
        if (idx < N_) local += deg[idx];
    }
    sums[t] = local;
    __syncthreads();
    for (int off = 1; off < SCAN_T; off <<= 1) {
        int v = sums[t];
        int add = (t >= off) ? sums[t - off] : 0;
        __syncthreads();
        sums[t] = v + add;
        __syncthreads();
    }
    int run = (t == 0) ? 0 : sums[t - 1];
    for (int i = 0; i < CHUNK; i++) {
        int idx = s0 + i;
        if (idx < N_) {
            rowStart[idx] = run;
            rowFill[idx] = run;
            run += deg[idx];
        }
    }
    if (t == SCAN_T - 1) rowStart[N_] = sums[SCAN_T - 1];
}

// ---------------- scatter edges into CSR-by-dst ----------------
__global__ void k_scatter(const int* __restrict__ ei, int* __restrict__ rowFill,
                          int* __restrict__ csr_src) {
    int e = blockIdx.x * 256 + threadIdx.x;
    if (e >= E_) return;
    int s = ei[e], d = ei[E_ + e];
    int p = atomicAdd(&rowFill[d], 1);
    csr_src[p] = s;
}

// ---------------- neigh mean -> bf16 hi/lo (one wave per node) ------
__global__ __launch_bounds__(256) void k_agg(const float* __restrict__ x,
                                             const int* __restrict__ rowStart,
                                             const int* __restrict__ csr_src,
                                             unsigned short* __restrict__ nhi,
                                             unsigned short* __restrict__ nlo) {
    int node = blockIdx.x * 4 + (threadIdx.x >> 6);
    int lane = threadIdx.x & 63;
    if (node >= N_) return;
    int a = rowStart[node], bnd = rowStart[node + 1];
    float ax = 0.f, ay = 0.f;
    int j = a;
    for (; j + 1 < bnd; j += 2) {
        int s0 = csr_src[j], s1 = csr_src[j + 1];
        float2 v0 = *(const float2*)(x + s0 * 128 + lane * 2);
        float2 v1 = *(const float2*)(x + s1 * 128 + lane * 2);
        ax += v0.x + v1.x;
        ay += v0.y + v1.y;
    }
    if (j < bnd) {
        int s0 = csr_src[j];
        float2 v0 = *(const float2*)(x + s0 * 128 + lane * 2);
        ax += v0.x;
        ay += v0.y;
    }
    float inv = 1.0f / (float)max(bnd - a, 1);
    ax *= inv;
    ay *= inv;
    HL hx = split2(ax), hy = split2(ay);
    ushort2v h, l;
    h.x = hx.h; h.y = hy.h;
    l.x = hx.l; l.y = hy.l;
    *(ushort2v*)(nhi + node * 128 + lane * 2) = h;
    *(ushort2v*)(nlo + node * 128 + lane * 2) = l;
}

// ---------------- x -> bf16 hi/lo ----------------
__global__ __launch_bounds__(256) void k_convx(const float* __restrict__ x,
                                               unsigned short* __restrict__ xhi,
                                               unsigned short* __restrict__ xlo) {
    int i4 = (blockIdx.x * 256 + threadIdx.x) * 4;
    if (i4 >= N_ * 128) return;
    float4 v = *(const float4*)(x + i4);
    HL a = split2(v.x), b = split2(v.y), c = split2(v.z), d = split2(v.w);
    ushort4v h, l;
    h.x = a.h; h.y = b.h; h.z = c.h; h.w = d.h;
    l.x = a.l; l.y = b.l; l.z = c.l; l.w = d.l;
    *(ushort4v*)(xhi + i4) = h;
    *(ushort4v*)(xlo + i4) = l;
}

// ---------------- W transposed -> bf16 hi/lo WT[j][k], plus bias ----------------
__global__ void k_prep(const float* __restrict__ We, const float* __restrict__ be,
                       const float* __restrict__ Wp, const float* __restrict__ bp,
                       unsigned short* __restrict__ WThi, unsigned short* __restrict__ WTlo,
                       float* __restrict__ bias) {
    int idx = blockIdx.x * 256 + threadIdx.x;
    if (idx < JTOT * KTOT) {
        int j = idx / KTOT, k = idx - j * KTOT;
        float v = (j < 128) ? We[k * 128 + j] : Wp[k * 256 + (j - 128)];
        HL s = split2(v);
        WThi[idx] = s.h;
        WTlo[idx] = s.l;
    }
    if (idx < JTOT) bias[idx] = (idx < 128) ? be[idx] : bp[idx - 128];
}

// ---------------- MFMA GEMM (bf16x3 split): [x|neigh] (N x 256) @ W (256 x 384) ----------------
// block tile 128x128, 4 waves (2x2), wave tile 64x64 = 4x4 mfma_16x16x32 tiles, BK=32
#define LDA 40  // row stride in ushorts: 80 B -> 16B-aligned rows, 2-way bank alias only
__global__ __launch_bounds__(256) void k_gemm(const unsigned short* __restrict__ xhi,
                                              const unsigned short* __restrict__ xlo,
                                              const unsigned short* __restrict__ nhi,
                                              const unsigned short* __restrict__ nlo,
                                              const unsigned short* __restrict__ WThi,
                                              const unsigned short* __restrict__ WTlo,
                                              const float* __restrict__ bias,
                                              float* __restrict__ embed,
                                              float* __restrict__ plog) {
    __shared__ unsigned short Ah[128][LDA], Al[128][LDA], Bh[128][LDA], Bl[128][LDA];
    int t = threadIdx.x;
    int wave = t >> 6, lane = t & 63;
    int wm = wave >> 1, wn = wave & 1;
    int q = lane >> 4, lr = lane & 15;
    int row0 = blockIdx.x * 128;
    int col0 = blockIdx.y * 128;

    f32x4 acc[4][4] = {};

    int sm = t >> 1;             // 0..127: row within tile
    int kc = (t & 1) * 16;       // 0 or 16

    for (int kt = 0; kt < KTOT; kt += 32) {
        const unsigned short* Ah_src = (kt < 128) ? xhi : nhi;
        const unsigned short* Al_src = (kt < 128) ? xlo : nlo;
        int kb = (kt & 127) + kc;
        int node = row0 + sm;
        short8 vh0 = {}, vh1 = {}, vl0 = {}, vl1 = {};
        if (node < N_) {
            const short8* ph = (const short8*)(Ah_src + (size_t)node * 128 + kb);
            const short8* pl = (const short8*)(Al_src + (size_t)node * 128 + kb);
            vh0 = ph[0]; vh1 = ph[1];
            vl0 = pl[0]; vl1 = pl[1];
        }
        *(short8*)&Ah[sm][kc] = vh0;
        *(short8*)&Ah[sm][kc + 8] = vh1;
        *(short8*)&Al[sm][kc] = vl0;
        *(short8*)&Al[sm][kc + 8] = vl1;
        {
            int j = col0 + sm;
            const short8* ph = (const short8*)(WThi + (size_t)j * 256 + kt + kc);
            const short8* pl = (const short8*)(WTlo + (size_t)j * 256 + kt + kc);
            short8 wh0 = ph[0], wh1 = ph[1];
            short8 wl0 = pl[0], wl1 = pl[1];
            *(short8*)&Bh[sm][kc] = wh0;
            *(short8*)&Bh[sm][kc + 8] = wh1;
            *(short8*)&Bl[sm][kc] = wl0;
            *(short8*)&Bl[sm][kc + 8] = wl1;
        }
        __syncthreads();

        short8 afh[4], afl[4];
#pragma unroll
        for (int mi = 0; mi < 4; mi++) {
            int r = wm * 64 + mi * 16 + lr;
            afh[mi] = *(const short8*)&Ah[r][q * 8];
            afl[mi] = *(const short8*)&Al[r][q * 8];
        }
#pragma unroll
        for (int ni = 0; ni < 4; ni++) {
            int r = wn * 64 + ni * 16 + lr;
            short8 bfh = *(const short8*)&Bh[r][q * 8];
            short8 bfl = *(const short8*)&Bl[r][q * 8];
#pragma unroll
            for (int mi = 0; mi < 4; mi++) {
                acc[mi][ni] = __builtin_amdgcn_mfma_f32_16x16x32_bf16(afh[mi], bfh, acc[mi][ni], 0, 0, 0);
                acc[mi][ni] = __builtin_amdgcn_mfma_f32_16x16x32_bf16(afh[mi], bfl, acc[mi][ni], 0, 0, 0);
                acc[mi][ni] = __builtin_amdgcn_mfma_f32_16x16x32_bf16(afl[mi], bfh, acc[mi][ni], 0, 0, 0);
            }
        }
        __syncthreads();
    }

    // epilogue: C/D layout col=lane&15, row=(lane>>4)*4+reg
#pragma unroll
    for (int ni = 0; ni < 4; ni++) {
        int col = col0 + wn * 64 + ni * 16 + lr;
        float bj = bias[col];
#pragma unroll
        for (int mi = 0; mi < 4; mi++) {
            int rbase = row0 + wm * 64 + mi * 16 + q * 4;
#pragma unroll
            for (int r = 0; r < 4; r++) {
                int row = rbase + r;
                if (row >= N_) continue;
                float v = acc[mi][ni][r] + bj;
                if (col < 128)
                    embed[(size_t)row * 128 + col] = v;
                else
                    plog[(size_t)row * 256 + (col - 128)] = v;
            }
        }
    }
}

// ---------------- double softmax -> compact r8[N][8] ----------------
__global__ __launch_bounds__(256) void k_r(const float* __restrict__ plog,
                                           const int* __restrict__ batch,
                                           float* __restrict__ r8) {
    int node = blockIdx.x * 4 + (threadIdx.x >> 6);
    int lane = threadIdx.x & 63;
    if (node >= N_) return;
    float4 p = *(const float4*)(plog + node * 256 + lane * 4);
    float m = fmaxf(fmaxf(p.x, p.y), fmaxf(p.z, p.w));
    for (int off = 32; off; off >>= 1) m = fmaxf(m, __shfl_xor(m, off, 64));
    float s = expf(p.x - m) + expf(p.y - m) + expf(p.z - m) + expf(p.w - m);
    for (int off = 32; off; off >>= 1) s += __shfl_xor(s, off, 64);
    int g = batch[node];
    float v = 0.f;
    if (lane < 8) v = expf(plog[node * 256 + g * 8 + lane] - m) / s;
    float M2 = v;
    for (int off = 4; off; off >>= 1) M2 = fmaxf(M2, __shfl_xor(M2, off, 64));
    float e = expf(v - M2);
    float Sg = e;
    for (int off = 4; off; off >>= 1) Sg += __shfl_xor(Sg, off, 64);
    float D2 = Sg + 248.0f * expf(-M2);
    float r = e / (Sg + 1e-13f * D2);
    if (lane < 8) r8[node * 8 + lane] = r;
}

// ---------------- h partials ----------------
__global__ __launch_bounds__(256) void k_h_part(const float* __restrict__ embed,
                                                const float* __restrict__ r8,
                                                float* __restrict__ partH) {
    int g = blockIdx.x;
    int c = blockIdx.y;
    int t = threadIdx.x;
    int o = t & 127, half = t >> 7;
    int n0g = (g * N_ + 31) >> 5;
    int n1g = ((g + 1) * N_ + 31) >> 5;
    int len = n1g - n0g;
    int a = n0g + (len * c) / HCHUNK;
    int b = n0g + (len * (c + 1)) / HCHUNK;
    float a0 = 0.f, a1 = 0.f, a2 = 0.f, a3 = 0.f;
#pragma unroll 4
    for (int n = a; n < b; n++) {
        float e = embed[n * 128 + o];
        const float* rr = r8 + n * 8 + half;
        a0 += rr[0] * e;
        a1 += rr[2] * e;
        a2 += rr[4] * e;
        a3 += rr[6] * e;
    }
    float* pb = partH + (g * HCHUNK + c) * 1024;
    pb[(half + 0) * 128 + o] = a0;
    pb[(half + 2) * 128 + o] = a1;
    pb[(half + 4) * 128 + o] = a2;
    pb[(half + 6) * 128 + o] = a3;
}

// ---------------- h reduce ----------------
__global__ __launch_bounds__(256) void k_h_red(const float* __restrict__ partH,
                                               float* __restrict__ out_h) {
    int idx = blockIdx.x * 256 + threadIdx.x;
    if (idx >= 256 * 128) return;
    int g = idx >> 10;
    int local = idx & 1023;
    float s = 0.f;
#pragma unroll
    for (int c = 0; c < HCHUNK; c++) s += partH[(g * HCHUNK + c) * 1024 + local];
    out_h[idx] = s;
}

// ---------------- adj partials from CSR ----------------
__global__ __launch_bounds__(256) void k_adj(const int* __restrict__ rowStart,
                                             const int* __restrict__ csr_src,
                                             const float* __restrict__ r8,
                                             float* __restrict__ partAdj) {
    __shared__ float lacc[4][2048];
    int gd = blockIdx.x;
    int c = blockIdx.y;
    int t = threadIdx.x;
    int w = t >> 6, lane = t & 63;
    int a = lane >> 3, b = lane & 7;
    for (int i = t; i < 4 * 2048; i += 256) ((float*)lacc)[i] = 0.f;
    __syncthreads();
    int n0g = (gd * N_ + 31) >> 5;
    int n1g = ((gd + 1) * N_ + 31) >> 5;
    int len = n1g - n0g;
    int na = n0g + (len * c) / ACHUNK;
    int nb = n0g + (len * (c + 1)) / ACHUNK;
    for (int n = na + w; n < nb; n += 4) {
        float rd = r8[n * 8 + b];
        int j0 = rowStart[n], j1 = rowStart[n + 1];
        for (int j = j0; j < j1; j++) {
            int s = csr_src[j];
            int gs = (s * B_) / N_;
            float v = r8[s * 8 + a] * rd;
            lacc[w][gs * 64 + lane] += v;
        }
    }
    __syncthreads();
    float* pb = partAdj + (gd * ACHUNK + c) * 2048;
    for (int i = t; i < 2048; i += 256)
        pb[i] = lacc[0][i] + lacc[1][i] + lacc[2][i] + lacc[3][i];
}

// ---------------- adj reduce ----------------
__global__ __launch_bounds__(256) void k_adj_red(const float* __restrict__ partAdj,
                                                 float* __restrict__ adj) {
    int o = blockIdx.x * 256 + threadIdx.x;
    if (o >= 256 * 256) return;
    int row = o >> 8, col = o & 255;
    int gs = row >> 3, a = row & 7;
    int gd = col >> 3, b = col & 7;
    int li = gs * 64 + a * 8 + b;
    float s = 0.f;
#pragma unroll
    for (int c = 0; c < ACHUNK; c++) s += partAdj[(gd * ACHUNK + c) * 2048 + li];
    adj[o] = s;
}

extern "C" void kernel_launch(void* const* d_in, const int* in_sizes, int n_in,
                              void* d_out, int out_size, void* d_ws, size_t ws_size,
                              hipStream_t stream) {
    const float* x = (const float*)d_in[0];
    const int* ei = (const int*)d_in[1];
    const int* batch = (const int*)d_in[2];
    const float* We = (const float*)d_in[3];
    const float* be = (const float*)d_in[4];
    const float* Wp = (const float*)d_in[5];
    const float* bp = (const float*)d_in[6];
    float* out = (float*)d_out;  // [adj 256*256 | h 256*128]

    char* w = (char*)d_ws;
    auto alloc = [&](size_t bytes) -> char* {
        char* p = w;
        w += (bytes + 255) & ~(size_t)255;
        return p;
    };
    unsigned short* xhi = (unsigned short*)alloc((size_t)N_ * 128 * 2);
    unsigned short* xlo = (unsigned short*)alloc((size_t)N_ * 128 * 2);
    unsigned short* nhi = (unsigned short*)alloc((size_t)N_ * 128 * 2);
    unsigned short* nlo = (unsigned short*)alloc((size_t)N_ * 128 * 2);
    unsigned short* WThi = (unsigned short*)alloc((size_t)JTOT * KTOT * 2);
    unsigned short* WTlo = (unsigned short*)alloc((size_t)JTOT * KTOT * 2);
    float* embed = (float*)alloc((size_t)N_ * 128 * 4);
    float* plog = (float*)alloc((size_t)N_ * 256 * 4);
    float* r8 = (float*)alloc((size_t)N_ * 8 * 4);
    float* bias = (float*)alloc(JTOT * 4);
    int* deg = (int*)alloc((size_t)N_ * 4);
    int* rowStart = (int*)alloc((size_t)(N_ + 1) * 4);
    int* rowFill = (int*)alloc((size_t)N_ * 4);
    int* csr_src = (int*)alloc((size_t)E_ * 4);
    float* partH = (float*)alloc((size_t)B_ * HCHUNK * 1024 * 4);
    float* partAdj = (float*)alloc((size_t)B_ * ACHUNK * 2048 * 4);

    (void)hipMemsetAsync(deg, 0, (size_t)N_ * 4, stream);

    k_hist<<<(E_ + 255) / 256, 256, 0, stream>>>(ei, deg);
    k_scan<<<1, SCAN_T, 0, stream>>>(deg, rowStart, rowFill);
    k_scatter<<<(E_ + 255) / 256, 256, 0, stream>>>(ei, rowFill, csr_src);
    k_convx<<<(N_ * 128 / 4 + 255) / 256, 256, 0, stream>>>(x, xhi, xlo);
    k_agg<<<(N_ + 3) / 4, 256, 0, stream>>>(x, rowStart, csr_src, nhi, nlo);
    k_prep<<<(JTOT * KTOT + 255) / 256, 256, 0, stream>>>(We, be, Wp, bp, WThi, WTlo, bias);
    dim3 gg((N_ + 127) / 128, JTOT / 128);
    k_gemm<<<gg, 256, 0, stream>>>(xhi, xlo, nhi, nlo, WThi, WTlo, bias, embed, plog);
    k_r<<<(N_ + 3) / 4, 256, 0, stream>>>(plog, batch, r8);
    dim3 hg(B_, HCHUNK);
    k_h_part<<<hg, 256, 0, stream>>>(embed, r8, partH);
    k_h_red<<<(256 * 128 + 255) / 256, 256, 0, stream>>>(partH, out + 256 * 256);
    dim3 ag(B_, ACHUNK);
    k_adj<<<ag, 256, 0, stream>>>(rowStart, csr_src, r8, partAdj);
    k_adj_red<<<(256 * 256 + 255) / 256, 256, 0, stream>>>(partAdj, out);
}